// Round 1
// baseline (888.258 us; speedup 1.0000x reference)
//
#include <hip/hip_runtime.h>
#include <math.h>

#define HID 256
#define NWG 64
#define BIGI (1 << 30)

// ---- workspace layout (4-byte units) ----
#define MM_OFF    0        // 64 images x 4 ints (xmin,xmax,ymin,ymax)
#define BAR_OFF   256      // 64 barriers x 64-int stride = 4096 ints
#define POS2T_OFF 4352     // pos2T[k][r], 256x64 floats
#define H1ST_OFF  20736    // h1sT[unit][r], 256x64 floats
#define HBUF_OFF  37120    // 2 x 1024 floats (double-buffered h)
// total ws need: 39168 * 4 = 156,672 bytes

// ---- output layout (floats) ----
#define OUT_DELTAS 0       // (4,5,4)
#define OUT_PBB    80      // (4,5,4)
#define OUT_LOC    160     // (4,5,2)
#define OUT_SCL    200     // (4,5,2)
#define OUT_MF     240     // (4,16,256)
#define OUT_CONF   16624   // (4,5)
#define OUT_BBOX   16644   // (4,16,4)

// ---- LDS layout for k_main (floats) ----
#define OFF_BBR   0        // 4: this wg's image bbox
#define OFF_P1    4        // 256: pos1 row
#define OFF_HP    260      // 4 rows x 264 (pad 8) = 1056, 16B aligned
#define OFF_SLAB  1316     // whh slab: 256k x 16cc packed float4-over-k = 4096
#define OFF_XG    5412     // xg[cc][r]: 16 x 64 = 1024
#define OFF_GATES 6436     // 4b x 16cc = 64
#define OFF_E     6500     // phase-E scratch: lh 1024, x1 1024, x2 512, c1 512, dl 80
#define SMEM_FLOATS 9652

__device__ __forceinline__ float sigmoidf_(float x) { return 1.0f / (1.0f + expf(-x)); }

__device__ __forceinline__ void gbar(int* ctrs, int bidx) {
    __syncthreads();
    if (threadIdx.x == 0) {
        int* c = ctrs + bidx * 64;
        __threadfence();  // release: publish this wg's global writes (device scope)
        __hip_atomic_fetch_add(c, 1, __ATOMIC_RELEASE, __HIP_MEMORY_SCOPE_AGENT);
        while (__hip_atomic_load(c, __ATOMIC_ACQUIRE, __HIP_MEMORY_SCOPE_AGENT) < NWG) {
            __builtin_amdgcn_s_sleep(1);
        }
        __threadfence();  // acquire: invalidate L1 so subsequent reads are fresh
    }
    __syncthreads();
}

// ---------------- kernel 1: init barrier counters + minmax sentinels ----------------
__global__ void k_init(int* ws) {
    int tid = threadIdx.x;
    ws[MM_OFF + tid] = (tid & 1) ? -1 : BIGI;  // [BIG, -1, BIG, -1] per image
    for (int i = 0; i < 16; ++i)
        ws[BAR_OFF + tid + i * 256] = 0;
}

// ---------------- kernel 2: per-image mask min/max ----------------
// grid = 64 images * 32 chunks, block = 256. Each thread: 32 float4 = 512B.
__global__ __launch_bounds__(256) void k_minmax(const float4* __restrict__ pred,
                                                int* __restrict__ mm) {
    int img = blockIdx.x >> 5;
    int chunk = blockIdx.x & 31;
    int tid = threadIdx.x;
    int base = img * 262144 + chunk * 8192 + tid;
    int xmn = BIGI, xmx = -1, ymn = BIGI, ymx = -1;
#pragma unroll 4
    for (int i = 0; i < 32; ++i) {
        int idx4 = base + i * 256;
        float4 v = pred[idx4];
        int x = (idx4 << 2) & 1023;
        int y = (idx4 >> 8) & 1023;
        bool m0 = v.x > 0.5f, m1 = v.y > 0.5f, m2 = v.z > 0.5f, m3 = v.w > 0.5f;
        int cmn = m0 ? x : (m1 ? x + 1 : (m2 ? x + 2 : (m3 ? x + 3 : BIGI)));
        int cmx = m3 ? x + 3 : (m2 ? x + 2 : (m1 ? x + 1 : (m0 ? x : -1)));
        xmn = min(xmn, cmn);
        xmx = max(xmx, cmx);
        if (m0 | m1 | m2 | m3) { ymn = min(ymn, y); ymx = max(ymx, y); }
    }
    // wave64 shuffle reduce
    for (int off = 32; off > 0; off >>= 1) {
        xmn = min(xmn, __shfl_down(xmn, off));
        xmx = max(xmx, __shfl_down(xmx, off));
        ymn = min(ymn, __shfl_down(ymn, off));
        ymx = max(ymx, __shfl_down(ymx, off));
    }
    __shared__ int red[4][4];
    int wave = tid >> 6;
    if ((tid & 63) == 0) { red[0][wave] = xmn; red[1][wave] = xmx; red[2][wave] = ymn; red[3][wave] = ymx; }
    __syncthreads();
    if (tid == 0) {
        xmn = min(min(red[0][0], red[0][1]), min(red[0][2], red[0][3]));
        xmx = max(max(red[1][0], red[1][1]), max(red[1][2], red[1][3]));
        ymn = min(min(red[2][0], red[2][1]), min(red[2][2], red[2][3]));
        ymx = max(max(red[3][0], red[3][1]), max(red[3][2], red[3][3]));
        atomicMin(&mm[img * 4 + 0], xmn);
        atomicMax(&mm[img * 4 + 1], xmx);
        atomicMin(&mm[img * 4 + 2], ymn);
        atomicMax(&mm[img * 4 + 3], ymx);
    }
}

// ---------------- kernel 3: persistent fused pos-MLP + 2-layer LSTM + heads ----------------
// 64 wgs x 256 threads. wg w owns hidden units [w*4, w*4+4) (16 gate cols).
__global__ __launch_bounds__(256, 1) void k_main(
    const float* __restrict__ pe_w1, const float* __restrict__ pe_b1,
    const float* __restrict__ pe_w2, const float* __restrict__ pe_b2,
    const float* __restrict__ wih0, const float* __restrict__ whh0,
    const float* __restrict__ bih0, const float* __restrict__ bhh0,
    const float* __restrict__ wih1, const float* __restrict__ whh1,
    const float* __restrict__ bih1, const float* __restrict__ bhh1,
    const float* __restrict__ mp_w1, const float* __restrict__ mp_b1,
    const float* __restrict__ mp_w2, const float* __restrict__ mp_b2,
    const float* __restrict__ mp_w3, const float* __restrict__ mp_b3,
    const float* __restrict__ cf_w1, const float* __restrict__ cf_b1,
    const float* __restrict__ cf_w2, const float* __restrict__ cf_b2,
    float* __restrict__ out, int* __restrict__ wsi, float* __restrict__ wsf) {
    __shared__ float smem[SMEM_FLOATS];
    const int tid = threadIdx.x;
    const int w = blockIdx.x;
    int* ctrs = wsi + BAR_OFF;
    float* pos2T = wsf + POS2T_OFF;
    float* h1sT = wsf + H1ST_OFF;
    float* hbuf = wsf + HBUF_OFF;
    int bidx = 0;

    // ---- Phase A: bbox for image w, pos-MLP row w, zero hbuf slice ----
    if (tid == 0) {
        int xmn = wsi[MM_OFF + w * 4 + 0], xmx = wsi[MM_OFF + w * 4 + 1];
        int ymn = wsi[MM_OFF + w * 4 + 2], ymx = wsi[MM_OFF + w * 4 + 3];
        float cx, cy, bw, bh;
        if (xmx >= 0) {
            cx = (float)(xmn + xmx) * (0.5f / 1024.0f);
            cy = (float)(ymn + ymx) * (0.5f / 1024.0f);
            bw = (float)(xmx - xmn) * (1.0f / 1024.0f);
            bh = (float)(ymx - ymn) * (1.0f / 1024.0f);
        } else { cx = 0.5f; cy = 0.5f; bw = 0.1f; bh = 0.1f; }
        smem[OFF_BBR + 0] = cx; smem[OFF_BBR + 1] = cy;
        smem[OFF_BBR + 2] = bw; smem[OFF_BBR + 3] = bh;
        out[OUT_BBOX + w * 4 + 0] = cx; out[OUT_BBOX + w * 4 + 1] = cy;
        out[OUT_BBOX + w * 4 + 2] = bw; out[OUT_BBOX + w * 4 + 3] = bh;
    }
    __syncthreads();
    {  // pos1[w][tid] = relu(bbox . pe_w1[:,tid] + pe_b1)
        float b0 = smem[OFF_BBR + 0], b1 = smem[OFF_BBR + 1];
        float b2 = smem[OFF_BBR + 2], b3 = smem[OFF_BBR + 3];
        float v = b0 * pe_w1[tid] + b1 * pe_w1[256 + tid] + b2 * pe_w1[512 + tid] +
                  b3 * pe_w1[768 + tid] + pe_b1[tid];
        smem[OFF_P1 + tid] = fmaxf(v, 0.0f);
    }
    __syncthreads();
    {  // pos2[w][tid] -> pos2T[tid*64 + w]
        float acc = pe_b2[tid];
#pragma unroll 4
        for (int k = 0; k < 256; ++k)
            acc += smem[OFF_P1 + k] * pe_w2[k * 256 + tid];
        pos2T[tid * 64 + w] = fmaxf(acc, 0.0f);
    }
    if (tid < 16) {  // zero this wg's slice of hbuf[0]
        int b = tid >> 2, u = tid & 3;
        hbuf[b * 256 + w * 4 + u] = 0.0f;
    }
    gbar(ctrs, bidx++);

    // ---- LSTM state ----
    float bhh_reg = 0.0f;
    float cstate = 0.0f;

    for (int layer = 0; layer < 2; ++layer) {
        // ---- load whh slab into LDS; compute xg slab into LDS ----
        const float* whh = (layer == 0) ? whh0 : whh1;
        const float* wih = (layer == 0) ? wih0 : wih1;
        const float* bih = (layer == 0) ? bih0 : bih1;
        const float* bhh = (layer == 0) ? bhh0 : bhh1;
        for (int i = tid; i < 4096; i += 256) {
            int k = i >> 4, cc = i & 15;
            int col = (cc >> 2) * 256 + w * 4 + (cc & 3);
            smem[OFF_SLAB + ((k >> 2) * 16 + cc) * 4 + (k & 3)] = whh[k * 1024 + col];
        }
        {  // xg[cc][r] = (layer0: pos2 row r) or (layer1: h1s row r) @ wih cols + bih
            int r = tid >> 2, cg = tid & 3;
            const float* wp = wih + cg * 256 + w * 4;
            float a0 = bih[cg * 256 + w * 4 + 0], a1 = bih[cg * 256 + w * 4 + 1];
            float a2 = bih[cg * 256 + w * 4 + 2], a3 = bih[cg * 256 + w * 4 + 3];
            const float* src = (layer == 0) ? pos2T : h1sT;
#pragma unroll 4
            for (int k = 0; k < 256; ++k) {
                float pv = src[k * 64 + r];
                float4 w4 = *(const float4*)(wp + k * 1024);
                a0 += pv * w4.x; a1 += pv * w4.y; a2 += pv * w4.z; a3 += pv * w4.w;
            }
            smem[OFF_XG + (cg * 4 + 0) * 64 + r] = a0;
            smem[OFF_XG + (cg * 4 + 1) * 64 + r] = a1;
            smem[OFF_XG + (cg * 4 + 2) * 64 + r] = a2;
            smem[OFF_XG + (cg * 4 + 3) * 64 + r] = a3;
        }
        if (tid < 64) {
            int cc = tid & 15;
            bhh_reg = bhh[(cc >> 2) * 256 + w * 4 + (cc & 3)];
        }
        cstate = 0.0f;
        if (layer == 1 && tid < 16) {  // reset h for layer1: zero hbuf[0] slice
            int b = tid >> 2, u = tid & 3;
            hbuf[b * 256 + w * 4 + u] = 0.0f;
        }
        gbar(ctrs, bidx++);

        // ---- 16 recurrent steps ----
        for (int t = 0; t < 16; ++t) {
            {  // stage h_prev (1024 floats) global -> LDS (padded rows of 264)
                float4 hv = ((const float4*)(hbuf + (t & 1) * 1024))[tid];
                int b = tid >> 6, k4 = tid & 63;
                ((float4*)(smem + OFF_HP))[b * 66 + k4] = hv;
            }
            __syncthreads();
            if (tid < 64) {  // gate dot: thread (b, cc)
                int b = tid >> 4, cc = tid & 15;
                float acc = smem[OFF_XG + cc * 64 + b * 16 + t] + bhh_reg;
                const float4* hp4 = (const float4*)(smem + OFF_HP) + b * 66;
                const float4* s4 = (const float4*)(smem + OFF_SLAB) + cc;
#pragma unroll 8
                for (int k4 = 0; k4 < 64; ++k4) {
                    float4 h4 = hp4[k4];
                    float4 wv = s4[k4 * 16];
                    acc += h4.x * wv.x + h4.y * wv.y + h4.z * wv.z + h4.w * wv.w;
                }
                smem[OFF_GATES + b * 16 + cc] = acc;
            }
            __syncthreads();
            if (tid < 16) {  // cell update: thread (b, u)
                int b = tid >> 2, u = tid & 3;
                float gi = smem[OFF_GATES + b * 16 + 0 + u];
                float gf = smem[OFF_GATES + b * 16 + 4 + u];
                float gg = smem[OFF_GATES + b * 16 + 8 + u];
                float go = smem[OFF_GATES + b * 16 + 12 + u];
                float i_ = sigmoidf_(gi), f_ = sigmoidf_(gf);
                float g_ = tanhf(gg), o_ = sigmoidf_(go);
                cstate = f_ * cstate + i_ * g_;
                float h = o_ * tanhf(cstate);
                int unit = w * 4 + u;
                hbuf[((t + 1) & 1) * 1024 + b * 256 + unit] = h;
                if (layer == 0) h1sT[unit * 64 + b * 16 + t] = h;
                else out[OUT_MF + (b * 16 + t) * 256 + unit] = h;
            }
            gbar(ctrs, bidx++);
        }
    }

    // ---- Phase E: heads (wg 0 only). last_hidden lives in hbuf[0..1024) ----
    if (w == 0) {
        float* lh = smem + OFF_E;
        float* x1 = lh + 1024;
        float* x2 = x1 + 1024;
        float* c1 = x2 + 512;
        float* dl = c1 + 512;
        {
            float4 v = ((const float4*)hbuf)[tid];
            ((float4*)lh)[tid] = v;
        }
        __syncthreads();
        {  // x1 = relu(lh @ mp_w1 + mp_b1)  (4 x 256)
            int bb = tid >> 6, c0 = (tid & 63) * 4;
            float a0 = mp_b1[c0], a1 = mp_b1[c0 + 1], a2 = mp_b1[c0 + 2], a3 = mp_b1[c0 + 3];
            const float* lhb = lh + bb * 256;
#pragma unroll 4
            for (int k = 0; k < 256; ++k) {
                float lv = lhb[k];
                float4 w4 = *(const float4*)(mp_w1 + k * 256 + c0);
                a0 += lv * w4.x; a1 += lv * w4.y; a2 += lv * w4.z; a3 += lv * w4.w;
            }
            x1[bb * 256 + c0 + 0] = fmaxf(a0, 0.0f);
            x1[bb * 256 + c0 + 1] = fmaxf(a1, 0.0f);
            x1[bb * 256 + c0 + 2] = fmaxf(a2, 0.0f);
            x1[bb * 256 + c0 + 3] = fmaxf(a3, 0.0f);
        }
        if (tid < 128) {  // c1 = relu(lh @ cf_w1 + cf_b1)  (4 x 128)
            int bb = tid >> 5, c0 = (tid & 31) * 4;
            float a0 = cf_b1[c0], a1 = cf_b1[c0 + 1], a2 = cf_b1[c0 + 2], a3 = cf_b1[c0 + 3];
            const float* lhb = lh + bb * 256;
#pragma unroll 4
            for (int k = 0; k < 256; ++k) {
                float lv = lhb[k];
                float4 w4 = *(const float4*)(cf_w1 + k * 128 + c0);
                a0 += lv * w4.x; a1 += lv * w4.y; a2 += lv * w4.z; a3 += lv * w4.w;
            }
            c1[bb * 128 + c0 + 0] = fmaxf(a0, 0.0f);
            c1[bb * 128 + c0 + 1] = fmaxf(a1, 0.0f);
            c1[bb * 128 + c0 + 2] = fmaxf(a2, 0.0f);
            c1[bb * 128 + c0 + 3] = fmaxf(a3, 0.0f);
        }
        __syncthreads();
        if (tid < 128) {  // x2 = relu(x1 @ mp_w2 + mp_b2)  (4 x 128)
            int bb = tid >> 5, c0 = (tid & 31) * 4;
            float a0 = mp_b2[c0], a1 = mp_b2[c0 + 1], a2 = mp_b2[c0 + 2], a3 = mp_b2[c0 + 3];
            const float* x1b = x1 + bb * 256;
#pragma unroll 4
            for (int k = 0; k < 256; ++k) {
                float xv = x1b[k];
                float4 w4 = *(const float4*)(mp_w2 + k * 128 + c0);
                a0 += xv * w4.x; a1 += xv * w4.y; a2 += xv * w4.z; a3 += xv * w4.w;
            }
            x2[bb * 128 + c0 + 0] = fmaxf(a0, 0.0f);
            x2[bb * 128 + c0 + 1] = fmaxf(a1, 0.0f);
            x2[bb * 128 + c0 + 2] = fmaxf(a2, 0.0f);
            x2[bb * 128 + c0 + 3] = fmaxf(a3, 0.0f);
        }
        __syncthreads();
        if (tid < 80) {  // deltas = x2 @ mp_w3 + mp_b3  (4 x 20)
            int bb = tid / 20, j = tid - bb * 20;
            float a = mp_b3[j];
            const float* x2b = x2 + bb * 128;
#pragma unroll 4
            for (int k = 0; k < 128; ++k) a += x2b[k] * mp_w3[k * 20 + j];
            dl[bb * 20 + j] = a;
            out[OUT_DELTAS + bb * 20 + j] = a;
        }
        if (tid >= 96 && tid < 116) {  // confidence = sigmoid(c1 @ cf_w2 + cf_b2)  (4 x 5)
            int idx = tid - 96;
            int bb = idx / 5, j = idx - bb * 5;
            float a = cf_b2[j];
            const float* c1b = c1 + bb * 128;
#pragma unroll 4
            for (int k = 0; k < 128; ++k) a += c1b[k] * cf_w2[k * 5 + j];
            out[OUT_CONF + bb * 5 + j] = sigmoidf_(a);
        }
        __syncthreads();
        if (tid < 16) {  // cumsum of deltas onto last bbox
            int bb = tid >> 2, j = tid & 3;
            int img = bb * 16 + 15;
            int xmn = wsi[MM_OFF + img * 4 + 0], xmx = wsi[MM_OFF + img * 4 + 1];
            int ymn = wsi[MM_OFF + img * 4 + 2], ymx = wsi[MM_OFF + img * 4 + 3];
            float v[4];
            if (xmx >= 0) {
                v[0] = (float)(xmn + xmx) * (0.5f / 1024.0f);
                v[1] = (float)(ymn + ymx) * (0.5f / 1024.0f);
                v[2] = (float)(xmx - xmn) * (1.0f / 1024.0f);
                v[3] = (float)(ymx - ymn) * (1.0f / 1024.0f);
            } else { v[0] = 0.5f; v[1] = 0.5f; v[2] = 0.1f; v[3] = 0.1f; }
            float acc = v[j];
            for (int h = 0; h < 5; ++h) {
                acc += dl[bb * 20 + h * 4 + j];
                out[OUT_PBB + bb * 20 + h * 4 + j] = acc;
                if (j < 2) out[OUT_LOC + bb * 10 + h * 2 + j] = acc;
                else out[OUT_SCL + bb * 10 + h * 2 + (j - 2)] = acc;
            }
        }
    }
}

extern "C" void kernel_launch(void* const* d_in, const int* in_sizes, int n_in,
                              void* d_out, int out_size, void* d_ws, size_t ws_size,
                              hipStream_t stream) {
    (void)in_sizes; (void)n_in; (void)out_size; (void)ws_size;
    const float* pred = (const float*)d_in[1];  // d_in[0] = features (unused by reference)
    const float* pe_w1 = (const float*)d_in[2];
    const float* pe_b1 = (const float*)d_in[3];
    const float* pe_w2 = (const float*)d_in[4];
    const float* pe_b2 = (const float*)d_in[5];
    const float* wih0 = (const float*)d_in[6];
    const float* whh0 = (const float*)d_in[7];
    const float* bih0 = (const float*)d_in[8];
    const float* bhh0 = (const float*)d_in[9];
    const float* wih1 = (const float*)d_in[10];
    const float* whh1 = (const float*)d_in[11];
    const float* bih1 = (const float*)d_in[12];
    const float* bhh1 = (const float*)d_in[13];
    const float* mp_w1 = (const float*)d_in[14];
    const float* mp_b1 = (const float*)d_in[15];
    const float* mp_w2 = (const float*)d_in[16];
    const float* mp_b2 = (const float*)d_in[17];
    const float* mp_w3 = (const float*)d_in[18];
    const float* mp_b3 = (const float*)d_in[19];
    const float* cf_w1 = (const float*)d_in[20];
    const float* cf_b1 = (const float*)d_in[21];
    const float* cf_w2 = (const float*)d_in[22];
    const float* cf_b2 = (const float*)d_in[23];
    float* out = (float*)d_out;
    int* wsi = (int*)d_ws;
    float* wsf = (float*)d_ws;

    hipLaunchKernelGGL(k_init, dim3(1), dim3(256), 0, stream, wsi);
    hipLaunchKernelGGL(k_minmax, dim3(64 * 32), dim3(256), 0, stream,
                       (const float4*)pred, wsi + MM_OFF);
    hipLaunchKernelGGL(k_main, dim3(NWG), dim3(256), 0, stream,
                       pe_w1, pe_b1, pe_w2, pe_b2,
                       wih0, whh0, bih0, bhh0,
                       wih1, whh1, bih1, bhh1,
                       mp_w1, mp_b1, mp_w2, mp_b2, mp_w3, mp_b3,
                       cf_w1, cf_b1, cf_w2, cf_b2,
                       out, wsi, wsf);
}

// Round 2
// 768.196 us; speedup vs baseline: 1.1563x; 1.1563x over previous
//
#include <hip/hip_runtime.h>
#include <math.h>

#define HID 256
#define NWG 64
#define BIGI (1 << 30)

// ---- workspace layout (4-byte units) ----
#define MM_OFF    0        // 64 images x 4 ints (xmin,xmax,ymin,ymax)
#define BAR_OFF   256      // 64 barriers x 64-int stride = 4096 ints
#define POS2T_OFF 4352     // pos2T[k][r], 256x64 floats
#define H1ST_OFF  20736    // h1sT[unit][r], 256x64 floats
#define HBUF_OFF  37120    // 2 x 1024 floats (double-buffered h)
// total ws need: 39168 * 4 = 156,672 bytes

// ---- output layout (floats) ----
#define OUT_DELTAS 0       // (4,5,4)
#define OUT_PBB    80      // (4,5,4)
#define OUT_LOC    160     // (4,5,2)
#define OUT_SCL    200     // (4,5,2)
#define OUT_MF     240     // (4,16,256)
#define OUT_CONF   16624   // (4,5)
#define OUT_BBOX   16644   // (4,16,4)

// ---- LDS layout for k_main (floats) ----
#define OFF_BBR   0        // 4: this wg's image bbox
#define OFF_P1    4        // 256: pos1 row
#define OFF_HP    260      // 4 rows x 264 (pad 8) = 1056, 16B aligned
#define OFF_SLAB  1316     // whh slab: 256k x 16cc packed float4-over-k = 4096
#define OFF_XG    5412     // xg[cc][r]: 16 x 64 = 1024
#define OFF_GATES 6436     // 4b x 16cc = 64
#define OFF_E     6500     // phase-E scratch: lh 1024, x1 1024, x2 512, c1 512, dl 80
#define SMEM_FLOATS 9652

__device__ __forceinline__ float sigmoidf_(float x) { return 1.0f / (1.0f + expf(-x)); }

// Coherent (device-scope, cache-bypassing) data movement. Relaxed ordering:
// visibility is guaranteed because these ops complete at the device coherence
// point, and gbar()'s __syncthreads drains vmcnt before the barrier arrive.
// NO acquire/release anywhere -> no buffer_inv / buffer_wbl2 L2 maintenance.
__device__ __forceinline__ void cstore(float* p, float v) {
    __hip_atomic_store(p, v, __ATOMIC_RELAXED, __HIP_MEMORY_SCOPE_AGENT);
}
__device__ __forceinline__ float cload(const float* p) {
    return __hip_atomic_load(p, __ATOMIC_RELAXED, __HIP_MEMORY_SCOPE_AGENT);
}

__device__ __forceinline__ void gbar(int* ctrs, int bidx) {
    // __syncthreads lowers to s_waitcnt vmcnt(0) lgkmcnt(0) + s_barrier:
    // all waves' coherent stores have reached the coherence point before arrive.
    __syncthreads();
    if (threadIdx.x == 0) {
        int* c = ctrs + bidx * 64;
        __hip_atomic_fetch_add(c, 1, __ATOMIC_RELAXED, __HIP_MEMORY_SCOPE_AGENT);
        while (__hip_atomic_load(c, __ATOMIC_RELAXED, __HIP_MEMORY_SCOPE_AGENT) < NWG) {
            __builtin_amdgcn_s_sleep(1);
        }
    }
    __syncthreads();
}

// ---------------- kernel 1: init barrier counters + minmax sentinels ----------------
__global__ void k_init(int* ws) {
    int tid = threadIdx.x;
    ws[MM_OFF + tid] = (tid & 1) ? -1 : BIGI;  // [BIG, -1, BIG, -1] per image
    for (int i = 0; i < 16; ++i)
        ws[BAR_OFF + tid + i * 256] = 0;
}

// ---------------- kernel 2: per-image mask min/max ----------------
// grid = 64 images * 32 chunks, block = 256. Each thread: 32 float4 = 512B.
__global__ __launch_bounds__(256) void k_minmax(const float4* __restrict__ pred,
                                                int* __restrict__ mm) {
    int img = blockIdx.x >> 5;
    int chunk = blockIdx.x & 31;
    int tid = threadIdx.x;
    int base = img * 262144 + chunk * 8192 + tid;
    int xmn = BIGI, xmx = -1, ymn = BIGI, ymx = -1;
#pragma unroll 4
    for (int i = 0; i < 32; ++i) {
        int idx4 = base + i * 256;
        float4 v = pred[idx4];
        int x = (idx4 << 2) & 1023;
        int y = (idx4 >> 8) & 1023;
        bool m0 = v.x > 0.5f, m1 = v.y > 0.5f, m2 = v.z > 0.5f, m3 = v.w > 0.5f;
        int cmn = m0 ? x : (m1 ? x + 1 : (m2 ? x + 2 : (m3 ? x + 3 : BIGI)));
        int cmx = m3 ? x + 3 : (m2 ? x + 2 : (m1 ? x + 1 : (m0 ? x : -1)));
        xmn = min(xmn, cmn);
        xmx = max(xmx, cmx);
        if (m0 | m1 | m2 | m3) { ymn = min(ymn, y); ymx = max(ymx, y); }
    }
    // wave64 shuffle reduce
    for (int off = 32; off > 0; off >>= 1) {
        xmn = min(xmn, __shfl_down(xmn, off));
        xmx = max(xmx, __shfl_down(xmx, off));
        ymn = min(ymn, __shfl_down(ymn, off));
        ymx = max(ymx, __shfl_down(ymx, off));
    }
    __shared__ int red[4][4];
    int wave = tid >> 6;
    if ((tid & 63) == 0) { red[0][wave] = xmn; red[1][wave] = xmx; red[2][wave] = ymn; red[3][wave] = ymx; }
    __syncthreads();
    if (tid == 0) {
        xmn = min(min(red[0][0], red[0][1]), min(red[0][2], red[0][3]));
        xmx = max(max(red[1][0], red[1][1]), max(red[1][2], red[1][3]));
        ymn = min(min(red[2][0], red[2][1]), min(red[2][2], red[2][3]));
        ymx = max(max(red[3][0], red[3][1]), max(red[3][2], red[3][3]));
        atomicMin(&mm[img * 4 + 0], xmn);
        atomicMax(&mm[img * 4 + 1], xmx);
        atomicMin(&mm[img * 4 + 2], ymn);
        atomicMax(&mm[img * 4 + 3], ymx);
    }
}

// ---------------- kernel 3: persistent fused pos-MLP + 2-layer LSTM + heads ----------------
// 64 wgs x 256 threads. wg w owns hidden units [w*4, w*4+4) (16 gate cols).
__global__ __launch_bounds__(256, 1) void k_main(
    const float* __restrict__ pe_w1, const float* __restrict__ pe_b1,
    const float* __restrict__ pe_w2, const float* __restrict__ pe_b2,
    const float* __restrict__ wih0, const float* __restrict__ whh0,
    const float* __restrict__ bih0, const float* __restrict__ bhh0,
    const float* __restrict__ wih1, const float* __restrict__ whh1,
    const float* __restrict__ bih1, const float* __restrict__ bhh1,
    const float* __restrict__ mp_w1, const float* __restrict__ mp_b1,
    const float* __restrict__ mp_w2, const float* __restrict__ mp_b2,
    const float* __restrict__ mp_w3, const float* __restrict__ mp_b3,
    const float* __restrict__ cf_w1, const float* __restrict__ cf_b1,
    const float* __restrict__ cf_w2, const float* __restrict__ cf_b2,
    float* __restrict__ out, int* __restrict__ wsi, float* __restrict__ wsf) {
    __shared__ float smem[SMEM_FLOATS];
    const int tid = threadIdx.x;
    const int w = blockIdx.x;
    int* ctrs = wsi + BAR_OFF;
    float* pos2T = wsf + POS2T_OFF;
    float* h1sT = wsf + H1ST_OFF;
    float* hbuf = wsf + HBUF_OFF;
    int bidx = 0;

    // ---- Phase A: bbox for image w, pos-MLP row w, zero hbuf slice ----
    if (tid == 0) {
        int xmn = wsi[MM_OFF + w * 4 + 0], xmx = wsi[MM_OFF + w * 4 + 1];
        int ymn = wsi[MM_OFF + w * 4 + 2], ymx = wsi[MM_OFF + w * 4 + 3];
        float cx, cy, bw, bh;
        if (xmx >= 0) {
            cx = (float)(xmn + xmx) * (0.5f / 1024.0f);
            cy = (float)(ymn + ymx) * (0.5f / 1024.0f);
            bw = (float)(xmx - xmn) * (1.0f / 1024.0f);
            bh = (float)(ymx - ymn) * (1.0f / 1024.0f);
        } else { cx = 0.5f; cy = 0.5f; bw = 0.1f; bh = 0.1f; }
        smem[OFF_BBR + 0] = cx; smem[OFF_BBR + 1] = cy;
        smem[OFF_BBR + 2] = bw; smem[OFF_BBR + 3] = bh;
        out[OUT_BBOX + w * 4 + 0] = cx; out[OUT_BBOX + w * 4 + 1] = cy;
        out[OUT_BBOX + w * 4 + 2] = bw; out[OUT_BBOX + w * 4 + 3] = bh;
    }
    __syncthreads();
    {  // pos1[w][tid] = relu(bbox . pe_w1[:,tid] + pe_b1)
        float b0 = smem[OFF_BBR + 0], b1 = smem[OFF_BBR + 1];
        float b2 = smem[OFF_BBR + 2], b3 = smem[OFF_BBR + 3];
        float v = b0 * pe_w1[tid] + b1 * pe_w1[256 + tid] + b2 * pe_w1[512 + tid] +
                  b3 * pe_w1[768 + tid] + pe_b1[tid];
        smem[OFF_P1 + tid] = fmaxf(v, 0.0f);
    }
    __syncthreads();
    {  // pos2[w][tid] -> pos2T[tid*64 + w]  (coherent store: read by all wgs)
        float acc = pe_b2[tid];
#pragma unroll 4
        for (int k = 0; k < 256; ++k)
            acc += smem[OFF_P1 + k] * pe_w2[k * 256 + tid];
        cstore(&pos2T[tid * 64 + w], fmaxf(acc, 0.0f));
    }
    if (tid < 16) {  // zero this wg's slice of hbuf[0]
        int b = tid >> 2, u = tid & 3;
        cstore(&hbuf[b * 256 + w * 4 + u], 0.0f);
    }
    gbar(ctrs, bidx++);

    // ---- LSTM state ----
    float bhh_reg = 0.0f;
    float cstate = 0.0f;

    for (int layer = 0; layer < 2; ++layer) {
        // ---- load whh slab into LDS; compute xg slab into LDS ----
        const float* whh = (layer == 0) ? whh0 : whh1;
        const float* wih = (layer == 0) ? wih0 : wih1;
        const float* bih = (layer == 0) ? bih0 : bih1;
        const float* bhh = (layer == 0) ? bhh0 : bhh1;
        for (int i = tid; i < 4096; i += 256) {
            int k = i >> 4, cc = i & 15;
            int col = (cc >> 2) * 256 + w * 4 + (cc & 3);
            smem[OFF_SLAB + ((k >> 2) * 16 + cc) * 4 + (k & 3)] = whh[k * 1024 + col];
        }
        {  // xg[cc][r] = (layer0: pos2 row r) or (layer1: h1s row r) @ wih cols + bih
            int r = tid >> 2, cg = tid & 3;
            const float* wp = wih + cg * 256 + w * 4;
            float a0 = bih[cg * 256 + w * 4 + 0], a1 = bih[cg * 256 + w * 4 + 1];
            float a2 = bih[cg * 256 + w * 4 + 2], a3 = bih[cg * 256 + w * 4 + 3];
            const float* src = (layer == 0) ? pos2T : h1sT;
#pragma unroll 4
            for (int k = 0; k < 256; ++k) {
                float pv = cload(&src[k * 64 + r]);
                float4 w4 = *(const float4*)(wp + k * 1024);
                a0 += pv * w4.x; a1 += pv * w4.y; a2 += pv * w4.z; a3 += pv * w4.w;
            }
            smem[OFF_XG + (cg * 4 + 0) * 64 + r] = a0;
            smem[OFF_XG + (cg * 4 + 1) * 64 + r] = a1;
            smem[OFF_XG + (cg * 4 + 2) * 64 + r] = a2;
            smem[OFF_XG + (cg * 4 + 3) * 64 + r] = a3;
        }
        if (tid < 64) {
            int cc = tid & 15;
            bhh_reg = bhh[(cc >> 2) * 256 + w * 4 + (cc & 3)];
        }
        cstate = 0.0f;
        if (layer == 1 && tid < 16) {  // reset h for layer1: zero hbuf[0] slice
            int b = tid >> 2, u = tid & 3;
            cstore(&hbuf[b * 256 + w * 4 + u], 0.0f);
        }
        // layer 0: nothing cross-wg was produced since the Phase-A barrier ->
        // skip the preamble barrier. layer 1: hbuf re-zero must be visible.
        if (layer == 1) gbar(ctrs, bidx);
        bidx++;

        // ---- 16 recurrent steps ----
        for (int t = 0; t < 16; ++t) {
            {  // stage h_prev (1024 floats) coherent-load -> LDS (padded rows of 264)
                int src = (t & 1) * 1024 + tid * 4;
                float4 hv;
                hv.x = cload(&hbuf[src + 0]);
                hv.y = cload(&hbuf[src + 1]);
                hv.z = cload(&hbuf[src + 2]);
                hv.w = cload(&hbuf[src + 3]);
                int b = tid >> 6, k4 = tid & 63;
                ((float4*)(smem + OFF_HP))[b * 66 + k4] = hv;
            }
            __syncthreads();
            if (tid < 64) {  // gate dot: thread (b, cc)
                int b = tid >> 4, cc = tid & 15;
                float acc = smem[OFF_XG + cc * 64 + b * 16 + t] + bhh_reg;
                const float4* hp4 = (const float4*)(smem + OFF_HP) + b * 66;
                const float4* s4 = (const float4*)(smem + OFF_SLAB) + cc;
#pragma unroll 8
                for (int k4 = 0; k4 < 64; ++k4) {
                    float4 h4 = hp4[k4];
                    float4 wv = s4[k4 * 16];
                    acc += h4.x * wv.x + h4.y * wv.y + h4.z * wv.z + h4.w * wv.w;
                }
                smem[OFF_GATES + b * 16 + cc] = acc;
            }
            __syncthreads();
            if (tid < 16) {  // cell update: thread (b, u)
                int b = tid >> 2, u = tid & 3;
                float gi = smem[OFF_GATES + b * 16 + 0 + u];
                float gf = smem[OFF_GATES + b * 16 + 4 + u];
                float gg = smem[OFF_GATES + b * 16 + 8 + u];
                float go = smem[OFF_GATES + b * 16 + 12 + u];
                float i_ = sigmoidf_(gi), f_ = sigmoidf_(gf);
                float g_ = tanhf(gg), o_ = sigmoidf_(go);
                cstate = f_ * cstate + i_ * g_;
                float h = o_ * tanhf(cstate);
                int unit = w * 4 + u;
                cstore(&hbuf[((t + 1) & 1) * 1024 + b * 256 + unit], h);
                if (layer == 0) cstore(&h1sT[unit * 64 + b * 16 + t], h);
                else out[OUT_MF + (b * 16 + t) * 256 + unit] = h;
            }
            gbar(ctrs, bidx++);
        }
    }

    // ---- Phase E: heads (wg 0 only). last_hidden lives in hbuf[0..1024) ----
    if (w == 0) {
        float* lh = smem + OFF_E;
        float* x1 = lh + 1024;
        float* x2 = x1 + 1024;
        float* c1 = x2 + 512;
        float* dl = c1 + 512;
        {
            lh[tid * 4 + 0] = cload(&hbuf[tid * 4 + 0]);
            lh[tid * 4 + 1] = cload(&hbuf[tid * 4 + 1]);
            lh[tid * 4 + 2] = cload(&hbuf[tid * 4 + 2]);
            lh[tid * 4 + 3] = cload(&hbuf[tid * 4 + 3]);
        }
        __syncthreads();
        {  // x1 = relu(lh @ mp_w1 + mp_b1)  (4 x 256)
            int bb = tid >> 6, c0 = (tid & 63) * 4;
            float a0 = mp_b1[c0], a1 = mp_b1[c0 + 1], a2 = mp_b1[c0 + 2], a3 = mp_b1[c0 + 3];
            const float* lhb = lh + bb * 256;
#pragma unroll 4
            for (int k = 0; k < 256; ++k) {
                float lv = lhb[k];
                float4 w4 = *(const float4*)(mp_w1 + k * 256 + c0);
                a0 += lv * w4.x; a1 += lv * w4.y; a2 += lv * w4.z; a3 += lv * w4.w;
            }
            x1[bb * 256 + c0 + 0] = fmaxf(a0, 0.0f);
            x1[bb * 256 + c0 + 1] = fmaxf(a1, 0.0f);
            x1[bb * 256 + c0 + 2] = fmaxf(a2, 0.0f);
            x1[bb * 256 + c0 + 3] = fmaxf(a3, 0.0f);
        }
        if (tid < 128) {  // c1 = relu(lh @ cf_w1 + cf_b1)  (4 x 128)
            int bb = tid >> 5, c0 = (tid & 31) * 4;
            float a0 = cf_b1[c0], a1 = cf_b1[c0 + 1], a2 = cf_b1[c0 + 2], a3 = cf_b1[c0 + 3];
            const float* lhb = lh + bb * 256;
#pragma unroll 4
            for (int k = 0; k < 256; ++k) {
                float lv = lhb[k];
                float4 w4 = *(const float4*)(cf_w1 + k * 128 + c0);
                a0 += lv * w4.x; a1 += lv * w4.y; a2 += lv * w4.z; a3 += lv * w4.w;
            }
            c1[bb * 128 + c0 + 0] = fmaxf(a0, 0.0f);
            c1[bb * 128 + c0 + 1] = fmaxf(a1, 0.0f);
            c1[bb * 128 + c0 + 2] = fmaxf(a2, 0.0f);
            c1[bb * 128 + c0 + 3] = fmaxf(a3, 0.0f);
        }
        __syncthreads();
        if (tid < 128) {  // x2 = relu(x1 @ mp_w2 + mp_b2)  (4 x 128)
            int bb = tid >> 5, c0 = (tid & 31) * 4;
            float a0 = mp_b2[c0], a1 = mp_b2[c0 + 1], a2 = mp_b2[c0 + 2], a3 = mp_b2[c0 + 3];
            const float* x1b = x1 + bb * 256;
#pragma unroll 4
            for (int k = 0; k < 256; ++k) {
                float xv = x1b[k];
                float4 w4 = *(const float4*)(mp_w2 + k * 128 + c0);
                a0 += xv * w4.x; a1 += xv * w4.y; a2 += xv * w4.z; a3 += xv * w4.w;
            }
            x2[bb * 128 + c0 + 0] = fmaxf(a0, 0.0f);
            x2[bb * 128 + c0 + 1] = fmaxf(a1, 0.0f);
            x2[bb * 128 + c0 + 2] = fmaxf(a2, 0.0f);
            x2[bb * 128 + c0 + 3] = fmaxf(a3, 0.0f);
        }
        __syncthreads();
        if (tid < 80) {  // deltas = x2 @ mp_w3 + mp_b3  (4 x 20)
            int bb = tid / 20, j = tid - bb * 20;
            float a = mp_b3[j];
            const float* x2b = x2 + bb * 128;
#pragma unroll 4
            for (int k = 0; k < 128; ++k) a += x2b[k] * mp_w3[k * 20 + j];
            dl[bb * 20 + j] = a;
            out[OUT_DELTAS + bb * 20 + j] = a;
        }
        if (tid >= 96 && tid < 116) {  // confidence = sigmoid(c1 @ cf_w2 + cf_b2)  (4 x 5)
            int idx = tid - 96;
            int bb = idx / 5, j = idx - bb * 5;
            float a = cf_b2[j];
            const float* c1b = c1 + bb * 128;
#pragma unroll 4
            for (int k = 0; k < 128; ++k) a += c1b[k] * cf_w2[k * 5 + j];
            out[OUT_CONF + bb * 5 + j] = sigmoidf_(a);
        }
        __syncthreads();
        if (tid < 16) {  // cumsum of deltas onto last bbox
            int bb = tid >> 2, j = tid & 3;
            int img = bb * 16 + 15;
            int xmn = wsi[MM_OFF + img * 4 + 0], xmx = wsi[MM_OFF + img * 4 + 1];
            int ymn = wsi[MM_OFF + img * 4 + 2], ymx = wsi[MM_OFF + img * 4 + 3];
            float v[4];
            if (xmx >= 0) {
                v[0] = (float)(xmn + xmx) * (0.5f / 1024.0f);
                v[1] = (float)(ymn + ymx) * (0.5f / 1024.0f);
                v[2] = (float)(xmx - xmn) * (1.0f / 1024.0f);
                v[3] = (float)(ymx - ymn) * (1.0f / 1024.0f);
            } else { v[0] = 0.5f; v[1] = 0.5f; v[2] = 0.1f; v[3] = 0.1f; }
            float acc = v[j];
            for (int h = 0; h < 5; ++h) {
                acc += dl[bb * 20 + h * 4 + j];
                out[OUT_PBB + bb * 20 + h * 4 + j] = acc;
                if (j < 2) out[OUT_LOC + bb * 10 + h * 2 + j] = acc;
                else out[OUT_SCL + bb * 10 + h * 2 + (j - 2)] = acc;
            }
        }
    }
}

extern "C" void kernel_launch(void* const* d_in, const int* in_sizes, int n_in,
                              void* d_out, int out_size, void* d_ws, size_t ws_size,
                              hipStream_t stream) {
    (void)in_sizes; (void)n_in; (void)out_size; (void)ws_size;
    const float* pred = (const float*)d_in[1];  // d_in[0] = features (unused by reference)
    const float* pe_w1 = (const float*)d_in[2];
    const float* pe_b1 = (const float*)d_in[3];
    const float* pe_w2 = (const float*)d_in[4];
    const float* pe_b2 = (const float*)d_in[5];
    const float* wih0 = (const float*)d_in[6];
    const float* whh0 = (const float*)d_in[7];
    const float* bih0 = (const float*)d_in[8];
    const float* bhh0 = (const float*)d_in[9];
    const float* wih1 = (const float*)d_in[10];
    const float* whh1 = (const float*)d_in[11];
    const float* bih1 = (const float*)d_in[12];
    const float* bhh1 = (const float*)d_in[13];
    const float* mp_w1 = (const float*)d_in[14];
    const float* mp_b1 = (const float*)d_in[15];
    const float* mp_w2 = (const float*)d_in[16];
    const float* mp_b2 = (const float*)d_in[17];
    const float* mp_w3 = (const float*)d_in[18];
    const float* mp_b3 = (const float*)d_in[19];
    const float* cf_w1 = (const float*)d_in[20];
    const float* cf_b1 = (const float*)d_in[21];
    const float* cf_w2 = (const float*)d_in[22];
    const float* cf_b2 = (const float*)d_in[23];
    float* out = (float*)d_out;
    int* wsi = (int*)d_ws;
    float* wsf = (float*)d_ws;

    hipLaunchKernelGGL(k_init, dim3(1), dim3(256), 0, stream, wsi);
    hipLaunchKernelGGL(k_minmax, dim3(64 * 32), dim3(256), 0, stream,
                       (const float4*)pred, wsi + MM_OFF);
    hipLaunchKernelGGL(k_main, dim3(NWG), dim3(256), 0, stream,
                       pe_w1, pe_b1, pe_w2, pe_b2,
                       wih0, whh0, bih0, bhh0,
                       wih1, whh1, bih1, bhh1,
                       mp_w1, mp_b1, mp_w2, mp_b2, mp_w3, mp_b3,
                       cf_w1, cf_b1, cf_w2, cf_b2,
                       out, wsi, wsf);
}